// Round 4
// baseline (706.735 us; speedup 1.0000x reference)
//
#include <hip/hip_runtime.h>
#include <hip/hip_bf16.h>
#include <cstdint>
#include <cstddef>

#define TT 2048
#define HH 1024
#define FF 2816
#define EE 8
#define BK 64
#define KT1 (HH / BK)   // 16
#define KT2 (FF / BK)   // 44
#define NROWS (TT * 2)  // total expert-assignment rows (top_k = 2)

typedef short bf16x8 __attribute__((ext_vector_type(8)));
typedef float f32x4v __attribute__((ext_vector_type(4)));
typedef float vf4    __attribute__((ext_vector_type(4)));
typedef unsigned int uint32;

__device__ __forceinline__ unsigned short f2bf(float f) {
    union { float f; uint32 u; } v; v.f = f;
    uint32 u = v.u;
    uint32 r = (u + 0x7FFFu + ((u >> 16) & 1u)) >> 16;  // RNE
    return (unsigned short)r;
}

// ---------------- router ----------------
__global__ void k_router(const float* __restrict__ x, const float* __restrict__ rw,
                         int* __restrict__ tke, float* __restrict__ tkw,
                         int* __restrict__ counts)
{
    int t = blockIdx.x * 4 + (threadIdx.x >> 6);
    int lane = threadIdx.x & 63;
    const float* xr = x + (size_t)t * HH;
    float acc[EE];
#pragma unroll
    for (int e = 0; e < EE; ++e) acc[e] = 0.f;
#pragma unroll
    for (int i = 0; i < HH / 64; ++i) {
        int h = i * 64 + lane;
        float xv = xr[h];
        const vf4* w = (const vf4*)(rw + (size_t)h * EE);
        vf4 w0 = w[0], w1 = w[1];
#pragma unroll
        for (int e = 0; e < 4; ++e) {
            acc[e]     = fmaf(xv, w0[e], acc[e]);
            acc[4 + e] = fmaf(xv, w1[e], acc[4 + e]);
        }
    }
#pragma unroll
    for (int e = 0; e < EE; ++e) {
        float v = acc[e];
#pragma unroll
        for (int m = 1; m < 64; m <<= 1) v += __shfl_xor(v, m, 64);
        acc[e] = v;
    }
    if (lane == 0) {
        int e1 = 0; float l1 = acc[0];
#pragma unroll
        for (int e = 1; e < EE; ++e) if (acc[e] > l1) { l1 = acc[e]; e1 = e; }
        int e2 = (e1 == 0) ? 1 : 0; float l2 = acc[e2];
#pragma unroll
        for (int e = 0; e < EE; ++e) if (e != e1 && acc[e] > l2) { l2 = acc[e]; e2 = e; }
        float w1 = 1.f / (1.f + __expf(l2 - l1));
        float w2 = 1.f - w1;
        tke[t * 2] = e1; tke[t * 2 + 1] = e2;
        tkw[t * 2] = w1; tkw[t * 2 + 1] = w2;
        atomicAdd(&counts[e1], 1);
        atomicAdd(&counts[e2], 1);
    }
}

// ---------------- x fp32 -> bf16 ----------------
__global__ void k_convert_x(const float* __restrict__ x, unsigned short* __restrict__ xb)
{
    int i = (blockIdx.x * 256 + threadIdx.x) * 8;
    vf4 a = *(const vf4*)(x + i);
    vf4 b = *(const vf4*)(x + i + 4);
    uint4 o;
    o.x = (uint32)f2bf(a[0]) | ((uint32)f2bf(a[1]) << 16);
    o.y = (uint32)f2bf(a[2]) | ((uint32)f2bf(a[3]) << 16);
    o.z = (uint32)f2bf(b[0]) | ((uint32)f2bf(b[1]) << 16);
    o.w = (uint32)f2bf(b[2]) | ((uint32)f2bf(b[3]) << 16);
    *(uint4*)(xb + i) = o;
}

// ---------------- offsets ----------------
__global__ void k_offsets(const int* __restrict__ counts, int* __restrict__ offs)
{
    if (threadIdx.x == 0) {
        int s = 0;
#pragma unroll
        for (int e = 0; e < EE; ++e) { offs[e] = s; s += counts[e]; }
        offs[EE] = s;
    }
}

// ---------------- scatter ----------------
__global__ void k_scatter(const int* __restrict__ tke, const float* __restrict__ tkw,
                          const int* __restrict__ offs, int* __restrict__ cursor,
                          int* __restrict__ row_tok, int* __restrict__ row_slot,
                          float* __restrict__ row_w)
{
    int t = blockIdx.x * 256 + threadIdx.x;
    if (t >= TT) return;
#pragma unroll
    for (int k = 0; k < 2; ++k) {
        int e = tke[t * 2 + k];
        int pos = atomicAdd(&cursor[e], 1);
        int r = offs[e] + pos;
        row_tok[r] = t;
        row_slot[r] = k;
        row_w[r] = tkw[t * 2 + k];
    }
}

// ---------------- GEMM1: h = silu(x*Wg)*(x*Wu); BM=128, BN=64 dual, 2-phase -------
__global__ __launch_bounds__(256, 4)
void k_gemm1(const unsigned short* __restrict__ xb,
             const float* __restrict__ wg, const float* __restrict__ wu,
             const int* __restrict__ offs, const int* __restrict__ row_tok,
             unsigned short* __restrict__ hb)
{
    // XCD-chunked swizzle over flat grid nwg = 44*128 = 5632 (div by 8)
    const int nwg = 44 * 16 * EE;
    int orig = blockIdx.x;
    int wgid = (orig & 7) * (nwg >> 3) + (orig >> 3);
    const int mt  = wgid & 15;      // fastest: mt shares the (e,nb) weight slab
    int tmp = wgid >> 4;
    const int nbt = tmp % 44;
    const int e   = tmp / 44;

    const int seg0 = offs[e];
    const int n_e  = offs[e + 1] - seg0;
    const int m0 = mt * 128;
    if (m0 >= n_e) return;
    const int nbase = nbt * 64;

    const float* Wg = wg + (size_t)e * HH * FF;
    const float* Wu = wu + (size_t)e * HH * FF;

    __shared__ __align__(16) unsigned char smem[32768];
    // A [0,16K): 128 rows x 128B swz ; Bg [16K,24K) ; Bu [24K,32K): 64 n-rows x 128B swz

    const int tid  = threadIdx.x;
    const int lane = tid & 63;
    const int wid  = tid >> 6;
    const int wr = wid >> 1, wc = wid & 1;

    int    a_lds[4];
    size_t a_gbl[4];
#pragma unroll
    for (int i = 0; i < 4; ++i) {
        int flat = tid + i * 256;
        int r  = flat >> 3;
        int cb = (flat & 7) * 16;
        int idx = m0 + r;
        int cidx = idx < n_e ? idx : (n_e - 1);
        int tok = row_tok[seg0 + cidx];
        a_gbl[i] = (size_t)tok * (HH * 2) + (size_t)cb;
        a_lds[i] = r * 128 + (cb ^ ((r & 7) << 4));
    }
    const int gn = tid & 15, gk = tid >> 4;
    const int bn0 = gn * 4, bk0 = gk * 4;
    int b_lds[4];
#pragma unroll
    for (int i = 0; i < 4; ++i) {
        int n = bn0 + i;
        b_lds[i] = n * 128 + ((bk0 * 2) ^ ((n & 7) << 4));
    }

    f32x4v zero4 = {0.f, 0.f, 0.f, 0.f};
    f32x4v accg[4][2], accu[4][2];
#pragma unroll
    for (int mi = 0; mi < 4; ++mi)
#pragma unroll
        for (int ni = 0; ni < 2; ++ni) { accg[mi][ni] = zero4; accu[mi][ni] = zero4; }

    const unsigned char* xbb = (const unsigned char*)xb;

    // prefetch registers
    uint4 av[4];
    vf4 bg4[4], bu4[4];

    // prologue: load tile 0
#pragma unroll
    for (int i = 0; i < 4; ++i) av[i] = *(const uint4*)(xbb + a_gbl[i]);
    {
        const float* wgr = Wg + (size_t)bk0 * FF + nbase + bn0;
        const float* wur = Wu + (size_t)bk0 * FF + nbase + bn0;
#pragma unroll
        for (int j = 0; j < 4; ++j) {
            bg4[j] = *(const vf4*)(wgr + (size_t)j * FF);
            bu4[j] = *(const vf4*)(wur + (size_t)j * FF);
        }
    }

    for (int kt = 0; kt < KT1; ++kt) {
        __syncthreads();   // LDS free (previous compute done)
#pragma unroll
        for (int i = 0; i < 4; ++i) *(uint4*)(smem + a_lds[i]) = av[i];
#pragma unroll
        for (int i = 0; i < 4; ++i) {
            uint2 vg, vu;
            vg.x = (uint32)f2bf(bg4[0][i]) | ((uint32)f2bf(bg4[1][i]) << 16);
            vg.y = (uint32)f2bf(bg4[2][i]) | ((uint32)f2bf(bg4[3][i]) << 16);
            vu.x = (uint32)f2bf(bu4[0][i]) | ((uint32)f2bf(bu4[1][i]) << 16);
            vu.y = (uint32)f2bf(bu4[2][i]) | ((uint32)f2bf(bu4[3][i]) << 16);
            *(uint2*)(smem + 16384 + b_lds[i]) = vg;
            *(uint2*)(smem + 24576 + b_lds[i]) = vu;
        }
        __syncthreads();   // tile kt ready
        // issue loads for kt+1 (overlap with compute below)
        if (kt + 1 < KT1) {
#pragma unroll
            for (int i = 0; i < 4; ++i)
                av[i] = *(const uint4*)(xbb + a_gbl[i] + (size_t)(kt + 1) * 128);
            const float* wgr = Wg + (size_t)((kt + 1) * BK + bk0) * FF + nbase + bn0;
            const float* wur = Wu + (size_t)((kt + 1) * BK + bk0) * FF + nbase + bn0;
#pragma unroll
            for (int j = 0; j < 4; ++j) {
                bg4[j] = *(const vf4*)(wgr + (size_t)j * FF);
                bu4[j] = *(const vf4*)(wur + (size_t)j * FF);
            }
        }
#pragma unroll
        for (int kk = 0; kk < 2; ++kk) {
            const int cb = kk * 64 + ((lane >> 4) << 4);
            bf16x8 af[4], bgf[2], buf_[2];
#pragma unroll
            for (int mi = 0; mi < 4; ++mi) {
                int r = wr * 64 + mi * 16 + (lane & 15);
                af[mi] = *(const bf16x8*)(smem + r * 128 + (cb ^ ((r & 7) << 4)));
            }
#pragma unroll
            for (int ni = 0; ni < 2; ++ni) {
                int n = wc * 32 + ni * 16 + (lane & 15);
                int off = n * 128 + (cb ^ ((n & 7) << 4));
                bgf[ni]  = *(const bf16x8*)(smem + 16384 + off);
                buf_[ni] = *(const bf16x8*)(smem + 24576 + off);
            }
#pragma unroll
            for (int mi = 0; mi < 4; ++mi)
#pragma unroll
                for (int ni = 0; ni < 2; ++ni) {
                    accg[mi][ni] = __builtin_amdgcn_mfma_f32_16x16x32_bf16(af[mi], bgf[ni],  accg[mi][ni], 0, 0, 0);
                    accu[mi][ni] = __builtin_amdgcn_mfma_f32_16x16x32_bf16(af[mi], buf_[ni], accu[mi][ni], 0, 0, 0);
                }
        }
    }

    const int lr = lane >> 4, lc = lane & 15;
#pragma unroll
    for (int mi = 0; mi < 4; ++mi) {
#pragma unroll
        for (int reg = 0; reg < 4; ++reg) {
            int r = wr * 64 + mi * 16 + lr * 4 + reg;
            int gi = m0 + r;
            if (gi < n_e) {
                size_t base = (size_t)(seg0 + gi) * FF;
#pragma unroll
                for (int ni = 0; ni < 2; ++ni) {
                    float g = accg[mi][ni][reg];
                    float u = accu[mi][ni][reg];
                    float hv = g * u / (1.f + __expf(-g));
                    int col = nbase + wc * 32 + ni * 16 + lc;
                    hb[base + col] = f2bf(hv);
                }
            }
        }
    }
}

// ---------------- GEMM2: y = h*Wd; BM=128, BN=128, split-K, 2-phase ----------------
__global__ __launch_bounds__(256, 4)
void k_gemm2(const unsigned short* __restrict__ hb, const float* __restrict__ wd,
             const int* __restrict__ offs, const int* __restrict__ row_tok,
             const int* __restrict__ row_slot, const float* __restrict__ row_w,
             float* __restrict__ opart, int ksn, int log2ks, int ktper)
{
    const int nwg = 8 * 16 * EE * ksn;
    int orig = blockIdx.x;
    int wgid = (orig & 7) * (nwg >> 3) + (orig >> 3);
    const int mt  = wgid & 15;                 // fastest: shares (e,ks,nb) B slab
    int tmp = wgid >> 4;
    const int nbt = tmp & 7;
    int tmp2 = tmp >> 3;                       // e*ksn + ks
    const int ks = tmp2 & (ksn - 1);
    const int e  = tmp2 >> log2ks;

    const int seg0 = offs[e];
    const int n_e  = offs[e + 1] - seg0;
    const int m0 = mt * 128;
    if (m0 >= n_e) return;
    const int nbase = nbt * 128;
    const int kt0 = ks * ktper;
    const float* W = wd + (size_t)e * FF * HH;

    __shared__ __align__(16) unsigned char smem[32768];
    // A [0,16K): 128 rows x 128B swz ; B [16K,32K): 128 n-rows x 128B swz

    const int tid  = threadIdx.x;
    const int lane = tid & 63;
    const int wid  = tid >> 6;
    const int wr = wid >> 1, wc = wid & 1;

    int    a_lds[4];
    size_t a_gbl[4];
#pragma unroll
    for (int i = 0; i < 4; ++i) {
        int flat = tid + i * 256;
        int r  = flat >> 3;
        int cb = (flat & 7) * 16;
        int idx = m0 + r;
        int cidx = idx < n_e ? idx : (n_e - 1);
        a_gbl[i] = (size_t)(seg0 + cidx) * (FF * 2) + (size_t)cb;
        a_lds[i] = r * 128 + (cb ^ ((r & 7) << 4));
    }
    // B staging: 512 slots (thread, s): 4n x 4k fp32 block each
    int b_lds[2][4];
    int b_bn0[2], b_bk0[2];
#pragma unroll
    for (int s = 0; s < 2; ++s) {
        int idx = tid + s * 256;
        b_bn0[s] = (idx & 31) * 4;
        b_bk0[s] = (idx >> 5) * 4;
#pragma unroll
        for (int i = 0; i < 4; ++i) {
            int n = b_bn0[s] + i;
            b_lds[s][i] = n * 128 + ((b_bk0[s] * 2) ^ ((n & 7) << 4));
        }
    }

    f32x4v zero4 = {0.f, 0.f, 0.f, 0.f};
    f32x4v acc[4][4];
#pragma unroll
    for (int mi = 0; mi < 4; ++mi)
#pragma unroll
        for (int ni = 0; ni < 4; ++ni) acc[mi][ni] = zero4;

    const unsigned char* hbb = (const unsigned char*)hb;

    uint4 av[4];
    vf4 b4[2][4];

    // prologue: load tile kt0
#pragma unroll
    for (int i = 0; i < 4; ++i)
        av[i] = *(const uint4*)(hbb + a_gbl[i] + (size_t)kt0 * 128);
#pragma unroll
    for (int s = 0; s < 2; ++s) {
        const float* wr_ = W + (size_t)(kt0 * BK + b_bk0[s]) * HH + nbase + b_bn0[s];
#pragma unroll
        for (int j = 0; j < 4; ++j)
            b4[s][j] = *(const vf4*)(wr_ + (size_t)j * HH);
    }

    for (int it = 0; it < ktper; ++it) {
        const int kt = kt0 + it;
        __syncthreads();
#pragma unroll
        for (int i = 0; i < 4; ++i) *(uint4*)(smem + a_lds[i]) = av[i];
#pragma unroll
        for (int s = 0; s < 2; ++s)
#pragma unroll
            for (int i = 0; i < 4; ++i) {
                uint2 v;
                v.x = (uint32)f2bf(b4[s][0][i]) | ((uint32)f2bf(b4[s][1][i]) << 16);
                v.y = (uint32)f2bf(b4[s][2][i]) | ((uint32)f2bf(b4[s][3][i]) << 16);
                *(uint2*)(smem + 16384 + b_lds[s][i]) = v;
            }
        __syncthreads();
        if (it + 1 < ktper) {
#pragma unroll
            for (int i = 0; i < 4; ++i)
                av[i] = *(const uint4*)(hbb + a_gbl[i] + (size_t)(kt + 1) * 128);
#pragma unroll
            for (int s = 0; s < 2; ++s) {
                const float* wr_ = W + (size_t)((kt + 1) * BK + b_bk0[s]) * HH + nbase + b_bn0[s];
#pragma unroll
                for (int j = 0; j < 4; ++j)
                    b4[s][j] = *(const vf4*)(wr_ + (size_t)j * HH);
            }
        }
#pragma unroll
        for (int kk = 0; kk < 2; ++kk) {
            const int cb = kk * 64 + ((lane >> 4) << 4);
            bf16x8 af[4], bf_[4];
#pragma unroll
            for (int mi = 0; mi < 4; ++mi) {
                int r = wr * 64 + mi * 16 + (lane & 15);
                af[mi] = *(const bf16x8*)(smem + r * 128 + (cb ^ ((r & 7) << 4)));
            }
#pragma unroll
            for (int ni = 0; ni < 4; ++ni) {
                int n = wc * 64 + ni * 16 + (lane & 15);
                bf_[ni] = *(const bf16x8*)(smem + 16384 + n * 128 + (cb ^ ((n & 7) << 4)));
            }
#pragma unroll
            for (int mi = 0; mi < 4; ++mi)
#pragma unroll
                for (int ni = 0; ni < 4; ++ni)
                    acc[mi][ni] = __builtin_amdgcn_mfma_f32_16x16x32_bf16(af[mi], bf_[ni], acc[mi][ni], 0, 0, 0);
        }
    }

    const int lr = lane >> 4, lc = lane & 15;
#pragma unroll
    for (int mi = 0; mi < 4; ++mi) {
#pragma unroll
        for (int reg = 0; reg < 4; ++reg) {
            int r = wr * 64 + mi * 16 + lr * 4 + reg;
            int gi = m0 + r;
            if (gi < n_e) {
                int ar  = seg0 + gi;
                int tok = row_tok[ar];
                int sl  = row_slot[ar];
                float wgt = row_w[ar];
                size_t base = ((size_t)(ks * 2 + sl) * TT + tok) * HH;
#pragma unroll
                for (int ni = 0; ni < 4; ++ni) {
                    int col = nbase + wc * 64 + ni * 16 + lc;
                    opart[base + col] = wgt * acc[mi][ni][reg];
                }
            }
        }
    }
}

// ---------------- combine: out = sum of nslice fp32 slices ----------------
__global__ void k_combine(const float* __restrict__ opart, float* __restrict__ out,
                          int nslice)
{
    int i = (blockIdx.x * 256 + threadIdx.x) * 4;
    vf4 s = {0.f, 0.f, 0.f, 0.f};
    for (int k = 0; k < nslice; ++k)
        s += *(const vf4*)(opart + (size_t)k * TT * HH + i);
    *(vf4*)(out + i) = s;
}

extern "C" void kernel_launch(void* const* d_in, const int* in_sizes, int n_in,
                              void* d_out, int out_size, void* d_ws, size_t ws_size,
                              hipStream_t stream)
{
    (void)in_sizes; (void)n_in; (void)out_size;
    const float* x  = (const float*)d_in[0];
    const float* rw = (const float*)d_in[1];
    const float* wg = (const float*)d_in[2];
    const float* wu = (const float*)d_in[3];
    const float* wd = (const float*)d_in[4];
    float* out = (float*)d_out;

    char* ws = (char*)d_ws;
    size_t off = 0;
    auto alloc = [&](size_t b) { size_t o = off; off += (b + 255) & ~(size_t)255; return o; };
    unsigned short* xb   = (unsigned short*)(ws + alloc((size_t)TT * HH * 2));
    int*   tke      = (int*)  (ws + alloc((size_t)TT * 2 * 4));
    float* tkw      = (float*)(ws + alloc((size_t)TT * 2 * 4));
    int*   counts   = (int*)  (ws + alloc(EE * 4));
    int*   cursor   = (int*)  (ws + alloc(EE * 4));
    int*   offs     = (int*)  (ws + alloc((EE + 1) * 4));
    int*   row_tok  = (int*)  (ws + alloc((size_t)NROWS * 4));
    int*   row_slot = (int*)  (ws + alloc((size_t)NROWS * 4));
    float* row_w    = (float*)(ws + alloc((size_t)NROWS * 4));
    unsigned short* hb = (unsigned short*)(ws + alloc((size_t)NROWS * FF * 2));

    // split-K factor: largest of {4,2,1} whose partial buffers fit the workspace
    size_t slice = (size_t)2 * TT * HH * 4;   // 2 slots per ks
    int KS = 4, LOG2KS = 2;
    if (off + 4 * slice > ws_size) { KS = 2; LOG2KS = 1; }
    if (off + 2 * slice > ws_size) { KS = 1; LOG2KS = 0; }
    float* opart = (float*)(ws + alloc((size_t)KS * slice));
    const int KTPER = KT2 / KS;               // 44/KS (11, 22, or 44)

    hipMemsetAsync(counts, 0, EE * 4, stream);
    hipMemsetAsync(cursor, 0, EE * 4, stream);

    k_convert_x<<<(TT * HH) / (256 * 8), 256, 0, stream>>>(x, xb);
    k_router<<<TT / 4, 256, 0, stream>>>(x, rw, tke, tkw, counts);
    k_offsets<<<1, 64, 0, stream>>>(counts, offs);
    k_scatter<<<(TT + 255) / 256, 256, 0, stream>>>(tke, tkw, offs, cursor,
                                                    row_tok, row_slot, row_w);
    k_gemm1<<<44 * 16 * EE, 256, 0, stream>>>(xb, wg, wu, offs, row_tok, hb);
    k_gemm2<<<8 * 16 * EE * KS, 256, 0, stream>>>(hb, wd, offs, row_tok, row_slot,
                                                  row_w, opart, KS, LOG2KS, KTPER);
    k_combine<<<(TT * HH) / (256 * 4), 256, 0, stream>>>(opart, out, KS * 2);
}

// Round 5
// 302.927 us; speedup vs baseline: 2.3330x; 2.3330x over previous
//
#include <hip/hip_runtime.h>
#include <hip/hip_bf16.h>
#include <cstdint>
#include <cstddef>

#define TT 2048
#define HH 1024
#define FF 2816
#define EE 8
#define BK 64
#define KT1 (HH / BK)   // 16
#define KT2 (FF / BK)   // 44
#define KS 4
#define KTPER (KT2 / KS) // 11
#define NROWS (TT * 2)

typedef short bf16x8 __attribute__((ext_vector_type(8)));
typedef float f32x4v __attribute__((ext_vector_type(4)));
typedef float vf4    __attribute__((ext_vector_type(4)));
typedef unsigned int uint32;

typedef __attribute__((address_space(3))) unsigned int lds_u32;
typedef const __attribute__((address_space(1))) unsigned int glb_u32;

__device__ __forceinline__ void gll16(const void* g, unsigned char* l) {
    __builtin_amdgcn_global_load_lds((glb_u32*)g, (lds_u32*)l, 16, 0, 0);
}

__device__ __forceinline__ unsigned short f2bf(float f) {
    union { float f; uint32 u; } v; v.f = f;
    uint32 u = v.u;
    uint32 r = (u + 0x7FFFu + ((u >> 16) & 1u)) >> 16;  // RNE
    return (unsigned short)r;
}

// ---------------- router ----------------
__global__ void k_router(const float* __restrict__ x, const float* __restrict__ rw,
                         int* __restrict__ tke, float* __restrict__ tkw,
                         int* __restrict__ counts)
{
    int t = blockIdx.x * 4 + (threadIdx.x >> 6);
    int lane = threadIdx.x & 63;
    const float* xr = x + (size_t)t * HH;
    float acc[EE];
#pragma unroll
    for (int e = 0; e < EE; ++e) acc[e] = 0.f;
#pragma unroll
    for (int i = 0; i < HH / 64; ++i) {
        int h = i * 64 + lane;
        float xv = xr[h];
        const vf4* w = (const vf4*)(rw + (size_t)h * EE);
        vf4 w0 = w[0], w1 = w[1];
#pragma unroll
        for (int e = 0; e < 4; ++e) {
            acc[e]     = fmaf(xv, w0[e], acc[e]);
            acc[4 + e] = fmaf(xv, w1[e], acc[4 + e]);
        }
    }
#pragma unroll
    for (int e = 0; e < EE; ++e) {
        float v = acc[e];
#pragma unroll
        for (int m = 1; m < 64; m <<= 1) v += __shfl_xor(v, m, 64);
        acc[e] = v;
    }
    if (lane == 0) {
        int e1 = 0; float l1 = acc[0];
#pragma unroll
        for (int e = 1; e < EE; ++e) if (acc[e] > l1) { l1 = acc[e]; e1 = e; }
        int e2 = (e1 == 0) ? 1 : 0; float l2 = acc[e2];
#pragma unroll
        for (int e = 0; e < EE; ++e) if (e != e1 && acc[e] > l2) { l2 = acc[e]; e2 = e; }
        float w1 = 1.f / (1.f + __expf(l2 - l1));
        float w2 = 1.f - w1;
        tke[t * 2] = e1; tke[t * 2 + 1] = e2;
        tkw[t * 2] = w1; tkw[t * 2 + 1] = w2;
        atomicAdd(&counts[e1], 1);
        atomicAdd(&counts[e2], 1);
    }
}

// ---------------- x fp32 -> bf16 ----------------
__global__ void k_convert_x(const float* __restrict__ x, unsigned short* __restrict__ xb)
{
    int i = (blockIdx.x * 256 + threadIdx.x) * 8;
    vf4 a = *(const vf4*)(x + i);
    vf4 b = *(const vf4*)(x + i + 4);
    uint4 o;
    o.x = (uint32)f2bf(a[0]) | ((uint32)f2bf(a[1]) << 16);
    o.y = (uint32)f2bf(a[2]) | ((uint32)f2bf(a[3]) << 16);
    o.z = (uint32)f2bf(b[0]) | ((uint32)f2bf(b[1]) << 16);
    o.w = (uint32)f2bf(b[2]) | ((uint32)f2bf(b[3]) << 16);
    *(uint4*)(xb + i) = o;
}

// ---------------- weight transpose + convert: [E][K][N] f32 -> [E][N][K] bf16 ------
__global__ __launch_bounds__(256)
void k_convert_wT(const float* __restrict__ src, unsigned short* __restrict__ dst,
                  int K, int N)
{
    const int nb = blockIdx.x * 64, kb = blockIdx.y * 64, e = blockIdx.z;
    __shared__ unsigned short t_[64][68];
    const int tid = threadIdx.x;
    const float* s = src + ((size_t)e * K + kb) * N + nb;
    {
        int kk = tid >> 4, n4 = (tid & 15) * 4;
#pragma unroll
        for (int i = 0; i < 4; ++i) {
            int k = kk + i * 16;
            vf4 v = *(const vf4*)(s + (size_t)k * N + n4);
#pragma unroll
            for (int j = 0; j < 4; ++j) t_[n4 + j][k] = f2bf(v[j]);
        }
    }
    __syncthreads();
    {
        int n = tid >> 2, c = (tid & 3) * 16;
        unsigned short* d = dst + ((size_t)e * N + nb + n) * K + kb + c;
        uint4 u0 = *(const uint4*)&t_[n][c];
        uint4 u1 = *(const uint4*)&t_[n][c + 8];
        *(uint4*)(d) = u0;
        *(uint4*)(d + 8) = u1;
    }
}

// ---------------- offsets ----------------
__global__ void k_offsets(const int* __restrict__ counts, int* __restrict__ offs)
{
    if (threadIdx.x == 0) {
        int s = 0;
#pragma unroll
        for (int e = 0; e < EE; ++e) { offs[e] = s; s += counts[e]; }
        offs[EE] = s;
    }
}

// ---------------- scatter ----------------
__global__ void k_scatter(const int* __restrict__ tke, const float* __restrict__ tkw,
                          const int* __restrict__ offs, int* __restrict__ cursor,
                          int* __restrict__ row_tok, int* __restrict__ row_slot,
                          float* __restrict__ row_w)
{
    int t = blockIdx.x * 256 + threadIdx.x;
    if (t >= TT) return;
#pragma unroll
    for (int k = 0; k < 2; ++k) {
        int e = tke[t * 2 + k];
        int pos = atomicAdd(&cursor[e], 1);
        int r = offs[e] + pos;
        row_tok[r] = t;
        row_slot[r] = k;
        row_w[r] = tkw[t * 2 + k];
    }
}

// ---------------- GEMM1: h = silu(x*WgT^t)*(x*WuT^t); BM=128,BN=64 dual, gload_lds --
__global__ __launch_bounds__(256, 2)
void k_gemm1(const unsigned short* __restrict__ xb,
             const unsigned short* __restrict__ wgT, const unsigned short* __restrict__ wuT,
             const int* __restrict__ offs, const int* __restrict__ row_tok,
             unsigned short* __restrict__ hb)
{
    const int nbase = blockIdx.x * 64;            // nbt fastest (round-3 order)
    const int e = blockIdx.y >> 4, mt = blockIdx.y & 15;
    const int seg0 = offs[e], n_e = offs[e + 1] - seg0;
    const int m0 = mt * 128;
    if (m0 >= n_e) return;

    __shared__ __align__(16) unsigned char smem[65536];  // 2 x (A 16K | Bg 8K | Bu 8K)
    const int tid = threadIdx.x, lane = tid & 63, wid = tid >> 6;
    const int wr = wid >> 1, wc = wid & 1;
    const int rl = lane >> 3, cbyte = (lane & 7) * 16;

    // pre-swizzled global sources: LDS slot (row, c) gets global (row, c ^ ((row&7)<<4))
    const char* a_src[4];
#pragma unroll
    for (int i = 0; i < 4; ++i) {
        int r = wid * 32 + i * 8 + rl;
        int gi = m0 + r; int cidx = gi < n_e ? gi : n_e - 1;
        int tok = row_tok[seg0 + cidx];
        a_src[i] = (const char*)xb + (size_t)tok * (HH * 2)
                 + (size_t)(cbyte ^ ((r & 7) << 4));
    }
    const char* bg_src[2]; const char* bu_src[2];
#pragma unroll
    for (int i = 0; i < 2; ++i) {
        int n = wid * 16 + i * 8 + rl;
        size_t rowoff = ((size_t)e * FF + nbase + n) * (HH * 2)
                      + (size_t)(cbyte ^ ((n & 7) << 4));
        bg_src[i] = (const char*)wgT + rowoff;
        bu_src[i] = (const char*)wuT + rowoff;
    }

    auto STAGE = [&](int c, int kt) {
        unsigned char* base = smem + c * 32768;
        size_t ko = (size_t)kt * 128;
#pragma unroll
        for (int i = 0; i < 4; ++i) gll16(a_src[i] + ko, base + wid * 4096 + i * 1024);
#pragma unroll
        for (int i = 0; i < 2; ++i) gll16(bg_src[i] + ko, base + 16384 + wid * 2048 + i * 1024);
#pragma unroll
        for (int i = 0; i < 2; ++i) gll16(bu_src[i] + ko, base + 24576 + wid * 2048 + i * 1024);
    };

    f32x4v zero4 = {0.f, 0.f, 0.f, 0.f};
    f32x4v accg[4][2], accu[4][2];
#pragma unroll
    for (int mi = 0; mi < 4; ++mi)
#pragma unroll
        for (int ni = 0; ni < 2; ++ni) { accg[mi][ni] = zero4; accu[mi][ni] = zero4; }

    STAGE(0, 0);
    __syncthreads();

    for (int kt = 0; kt < KT1; ++kt) {
        int cur = kt & 1;
        if (kt + 1 < KT1) STAGE(cur ^ 1, kt + 1);
        unsigned char* buf = smem + cur * 32768;
#pragma unroll
        for (int kk = 0; kk < 2; ++kk) {
            const int cb = kk * 64 + ((lane >> 4) << 4);
            bf16x8 af[4], bgf[2], buf_[2];
#pragma unroll
            for (int mi = 0; mi < 4; ++mi) {
                int r = wr * 64 + mi * 16 + (lane & 15);
                af[mi] = *(const bf16x8*)(buf + r * 128 + (cb ^ ((r & 7) << 4)));
            }
#pragma unroll
            for (int ni = 0; ni < 2; ++ni) {
                int n = wc * 32 + ni * 16 + (lane & 15);
                int off = n * 128 + (cb ^ ((n & 7) << 4));
                bgf[ni]  = *(const bf16x8*)(buf + 16384 + off);
                buf_[ni] = *(const bf16x8*)(buf + 24576 + off);
            }
#pragma unroll
            for (int mi = 0; mi < 4; ++mi)
#pragma unroll
                for (int ni = 0; ni < 2; ++ni) {
                    accg[mi][ni] = __builtin_amdgcn_mfma_f32_16x16x32_bf16(af[mi], bgf[ni],  accg[mi][ni], 0, 0, 0);
                    accu[mi][ni] = __builtin_amdgcn_mfma_f32_16x16x32_bf16(af[mi], buf_[ni], accu[mi][ni], 0, 0, 0);
                }
        }
        __syncthreads();
    }

    const int lr = lane >> 4, lc = lane & 15;
#pragma unroll
    for (int mi = 0; mi < 4; ++mi) {
#pragma unroll
        for (int reg = 0; reg < 4; ++reg) {
            int r = wr * 64 + mi * 16 + lr * 4 + reg;
            int gi = m0 + r;
            if (gi < n_e) {
                size_t base = (size_t)(seg0 + gi) * FF;
#pragma unroll
                for (int ni = 0; ni < 2; ++ni) {
                    float g = accg[mi][ni][reg];
                    float u = accu[mi][ni][reg];
                    float hv = g * u / (1.f + __expf(-g));
                    int col = nbase + wc * 32 + ni * 16 + lc;
                    hb[base + col] = f2bf(hv);
                }
            }
        }
    }
}

// ---------------- GEMM2: y = h*WdT^t; BM=128,BN=128, split-K=4, gload_lds ----------
__global__ __launch_bounds__(256, 2)
void k_gemm2(const unsigned short* __restrict__ hb, const unsigned short* __restrict__ wdT,
             const int* __restrict__ offs, const int* __restrict__ row_tok,
             const int* __restrict__ row_slot, const float* __restrict__ row_w,
             float* __restrict__ opart)
{
    const int nbase = blockIdx.x * 128;
    const int e = blockIdx.y >> 4, mt = blockIdx.y & 15;
    const int ks = blockIdx.z;
    const int seg0 = offs[e], n_e = offs[e + 1] - seg0;
    const int m0 = mt * 128;
    if (m0 >= n_e) return;
    const int kt0 = ks * KTPER;

    __shared__ __align__(16) unsigned char smem[65536];  // 2 x (A 16K | B 16K)
    const int tid = threadIdx.x, lane = tid & 63, wid = tid >> 6;
    const int wr = wid >> 1, wc = wid & 1;
    const int rl = lane >> 3, cbyte = (lane & 7) * 16;

    const char* a_src[4];
#pragma unroll
    for (int i = 0; i < 4; ++i) {
        int r = wid * 32 + i * 8 + rl;
        int gi = m0 + r; int cidx = gi < n_e ? gi : n_e - 1;
        a_src[i] = (const char*)hb + (size_t)(seg0 + cidx) * (FF * 2)
                 + (size_t)(cbyte ^ ((r & 7) << 4));
    }
    const char* b_src[4];
#pragma unroll
    for (int i = 0; i < 4; ++i) {
        int n = wid * 32 + i * 8 + rl;
        b_src[i] = (const char*)wdT + ((size_t)e * HH + nbase + n) * (FF * 2)
                 + (size_t)(cbyte ^ ((n & 7) << 4));
    }

    auto STAGE = [&](int c, int kt) {
        unsigned char* base = smem + c * 32768;
        size_t ko = (size_t)kt * 128;
#pragma unroll
        for (int i = 0; i < 4; ++i) gll16(a_src[i] + ko, base + wid * 4096 + i * 1024);
#pragma unroll
        for (int i = 0; i < 4; ++i) gll16(b_src[i] + ko, base + 16384 + wid * 4096 + i * 1024);
    };

    f32x4v zero4 = {0.f, 0.f, 0.f, 0.f};
    f32x4v acc[4][4];
#pragma unroll
    for (int mi = 0; mi < 4; ++mi)
#pragma unroll
        for (int ni = 0; ni < 4; ++ni) acc[mi][ni] = zero4;

    STAGE(0, kt0);
    __syncthreads();

    for (int it = 0; it < KTPER; ++it) {
        int cur = it & 1;
        if (it + 1 < KTPER) STAGE(cur ^ 1, kt0 + it + 1);
        unsigned char* buf = smem + cur * 32768;
#pragma unroll
        for (int kk = 0; kk < 2; ++kk) {
            const int cb = kk * 64 + ((lane >> 4) << 4);
            bf16x8 af[4], bf_[4];
#pragma unroll
            for (int mi = 0; mi < 4; ++mi) {
                int r = wr * 64 + mi * 16 + (lane & 15);
                af[mi] = *(const bf16x8*)(buf + r * 128 + (cb ^ ((r & 7) << 4)));
            }
#pragma unroll
            for (int ni = 0; ni < 4; ++ni) {
                int n = wc * 64 + ni * 16 + (lane & 15);
                bf_[ni] = *(const bf16x8*)(buf + 16384 + n * 128 + (cb ^ ((n & 7) << 4)));
            }
#pragma unroll
            for (int mi = 0; mi < 4; ++mi)
#pragma unroll
                for (int ni = 0; ni < 4; ++ni)
                    acc[mi][ni] = __builtin_amdgcn_mfma_f32_16x16x32_bf16(af[mi], bf_[ni], acc[mi][ni], 0, 0, 0);
        }
        __syncthreads();
    }

    const int lr = lane >> 4, lc = lane & 15;
#pragma unroll
    for (int mi = 0; mi < 4; ++mi) {
#pragma unroll
        for (int reg = 0; reg < 4; ++reg) {
            int r = wr * 64 + mi * 16 + lr * 4 + reg;
            int gi = m0 + r;
            if (gi < n_e) {
                int ar  = seg0 + gi;
                int tok = row_tok[ar];
                int sl  = row_slot[ar];
                float wgt = row_w[ar];
                size_t base = ((size_t)(ks * 2 + sl) * TT + tok) * HH;
#pragma unroll
                for (int ni = 0; ni < 4; ++ni) {
                    int col = nbase + wc * 64 + ni * 16 + lc;
                    opart[base + col] = wgt * acc[mi][ni][reg];
                }
            }
        }
    }
}

// ---------------- combine: out = sum of 8 fp32 slices ----------------
__global__ void k_combine(const float* __restrict__ opart, float* __restrict__ out)
{
    int i = (blockIdx.x * 256 + threadIdx.x) * 4;
    vf4 s = {0.f, 0.f, 0.f, 0.f};
#pragma unroll
    for (int k = 0; k < KS * 2; ++k)
        s += *(const vf4*)(opart + (size_t)k * TT * HH + i);
    *(vf4*)(out + i) = s;
}

extern "C" void kernel_launch(void* const* d_in, const int* in_sizes, int n_in,
                              void* d_out, int out_size, void* d_ws, size_t ws_size,
                              hipStream_t stream)
{
    (void)in_sizes; (void)n_in; (void)out_size; (void)ws_size;
    const float* x  = (const float*)d_in[0];
    const float* rw = (const float*)d_in[1];
    const float* wg = (const float*)d_in[2];
    const float* wu = (const float*)d_in[3];
    const float* wd = (const float*)d_in[4];
    float* out = (float*)d_out;

    char* ws = (char*)d_ws;
    size_t off = 0;
    auto alloc = [&](size_t b) { size_t o = off; off += (b + 255) & ~(size_t)255; return o; };
    unsigned short* xb  = (unsigned short*)(ws + alloc((size_t)TT * HH * 2));
    unsigned short* wgT = (unsigned short*)(ws + alloc((size_t)EE * FF * HH * 2));
    unsigned short* wuT = (unsigned short*)(ws + alloc((size_t)EE * FF * HH * 2));
    unsigned short* wdT = (unsigned short*)(ws + alloc((size_t)EE * HH * FF * 2));
    int*   tke      = (int*)  (ws + alloc((size_t)TT * 2 * 4));
    float* tkw      = (float*)(ws + alloc((size_t)TT * 2 * 4));
    int*   counts   = (int*)  (ws + alloc(EE * 4));
    int*   cursor   = (int*)  (ws + alloc(EE * 4));
    int*   offs     = (int*)  (ws + alloc((EE + 1) * 4));
    int*   row_tok  = (int*)  (ws + alloc((size_t)NROWS * 4));
    int*   row_slot = (int*)  (ws + alloc((size_t)NROWS * 4));
    float* row_w    = (float*)(ws + alloc((size_t)NROWS * 4));
    unsigned short* hb = (unsigned short*)(ws + alloc((size_t)NROWS * FF * 2));
    // opart (8 slices x 8.4 MB = 67 MB) aliases the wgT+wuT region (92 MB),
    // which is dead after k_gemm1 completes (stream-ordered before k_gemm2).
    float* opart = (float*)wgT;

    hipMemsetAsync(counts, 0, EE * 4, stream);
    hipMemsetAsync(cursor, 0, EE * 4, stream);

    k_convert_x<<<(TT * HH) / (256 * 8), 256, 0, stream>>>(x, xb);
    {
        dim3 gw(FF / 64, HH / 64, EE);   // wg/wu: K=HH, N=FF
        k_convert_wT<<<gw, 256, 0, stream>>>(wg, wgT, HH, FF);
        k_convert_wT<<<gw, 256, 0, stream>>>(wu, wuT, HH, FF);
        dim3 gd(HH / 64, FF / 64, EE);   // wd: K=FF, N=HH
        k_convert_wT<<<gd, 256, 0, stream>>>(wd, wdT, FF, HH);
    }
    k_router<<<TT / 4, 256, 0, stream>>>(x, rw, tke, tkw, counts);
    k_offsets<<<1, 64, 0, stream>>>(counts, offs);
    k_scatter<<<(TT + 255) / 256, 256, 0, stream>>>(tke, tkw, offs, cursor,
                                                    row_tok, row_slot, row_w);
    dim3 g1(FF / 64, 16 * EE);
    k_gemm1<<<g1, 256, 0, stream>>>(xb, wgT, wuT, offs, row_tok, hb);
    dim3 g2(HH / 128, 16 * EE, KS);
    k_gemm2<<<g2, 256, 0, stream>>>(hb, wdT, offs, row_tok, row_slot, row_w, opart);
    k_combine<<<(TT * HH) / (256 * 4), 256, 0, stream>>>(opart, out);
}

// Round 6
// 292.340 us; speedup vs baseline: 2.4175x; 1.0362x over previous
//
#include <hip/hip_runtime.h>
#include <hip/hip_bf16.h>
#include <cstdint>
#include <cstddef>

#define TT 2048
#define HH 1024
#define FF 2816
#define EE 8
#define BK 64
#define KT1 (HH / BK)   // 16
#define KT2 (FF / BK)   // 44
#define KS 4
#define KTPER (KT2 / KS) // 11
#define NROWS (TT * 2)

typedef short bf16x8 __attribute__((ext_vector_type(8)));
typedef float f32x4v __attribute__((ext_vector_type(4)));
typedef float vf4    __attribute__((ext_vector_type(4)));
typedef unsigned int uint32;

typedef __attribute__((address_space(3))) unsigned int lds_u32;
typedef const __attribute__((address_space(1))) unsigned int glb_u32;

__device__ __forceinline__ void gll16(const void* g, unsigned char* l) {
    __builtin_amdgcn_global_load_lds((glb_u32*)g, (lds_u32*)l, 16, 0, 0);
}

__device__ __forceinline__ unsigned short f2bf(float f) {
    union { float f; uint32 u; } v; v.f = f;
    uint32 u = v.u;
    uint32 r = (u + 0x7FFFu + ((u >> 16) & 1u)) >> 16;  // RNE
    return (unsigned short)r;
}

// ---------------- router ----------------
__global__ void k_router(const float* __restrict__ x, const float* __restrict__ rw,
                         int* __restrict__ tke, float* __restrict__ tkw,
                         int* __restrict__ counts)
{
    int t = blockIdx.x * 4 + (threadIdx.x >> 6);
    int lane = threadIdx.x & 63;
    const float* xr = x + (size_t)t * HH;
    float acc[EE];
#pragma unroll
    for (int e = 0; e < EE; ++e) acc[e] = 0.f;
#pragma unroll
    for (int i = 0; i < HH / 64; ++i) {
        int h = i * 64 + lane;
        float xv = xr[h];
        const vf4* w = (const vf4*)(rw + (size_t)h * EE);
        vf4 w0 = w[0], w1 = w[1];
#pragma unroll
        for (int e = 0; e < 4; ++e) {
            acc[e]     = fmaf(xv, w0[e], acc[e]);
            acc[4 + e] = fmaf(xv, w1[e], acc[4 + e]);
        }
    }
#pragma unroll
    for (int e = 0; e < EE; ++e) {
        float v = acc[e];
#pragma unroll
        for (int m = 1; m < 64; m <<= 1) v += __shfl_xor(v, m, 64);
        acc[e] = v;
    }
    if (lane == 0) {
        int e1 = 0; float l1 = acc[0];
#pragma unroll
        for (int e = 1; e < EE; ++e) if (acc[e] > l1) { l1 = acc[e]; e1 = e; }
        int e2 = (e1 == 0) ? 1 : 0; float l2 = acc[e2];
#pragma unroll
        for (int e = 0; e < EE; ++e) if (e != e1 && acc[e] > l2) { l2 = acc[e]; e2 = e; }
        float w1 = 1.f / (1.f + __expf(l2 - l1));
        float w2 = 1.f - w1;
        tke[t * 2] = e1; tke[t * 2 + 1] = e2;
        tkw[t * 2] = w1; tkw[t * 2 + 1] = w2;
        atomicAdd(&counts[e1], 1);
        atomicAdd(&counts[e2], 1);
    }
}

// ---------------- x fp32 -> bf16 ----------------
__global__ void k_convert_x(const float* __restrict__ x, unsigned short* __restrict__ xb)
{
    int i = (blockIdx.x * 256 + threadIdx.x) * 8;
    vf4 a = *(const vf4*)(x + i);
    vf4 b = *(const vf4*)(x + i + 4);
    uint4 o;
    o.x = (uint32)f2bf(a[0]) | ((uint32)f2bf(a[1]) << 16);
    o.y = (uint32)f2bf(a[2]) | ((uint32)f2bf(a[3]) << 16);
    o.z = (uint32)f2bf(b[0]) | ((uint32)f2bf(b[1]) << 16);
    o.w = (uint32)f2bf(b[2]) | ((uint32)f2bf(b[3]) << 16);
    *(uint4*)(xb + i) = o;
}

// ---------------- weight transpose + convert: [E][K][N] f32 -> [E][N][K] bf16 ------
__global__ __launch_bounds__(256)
void k_convert_wT(const float* __restrict__ src, unsigned short* __restrict__ dst,
                  int K, int N)
{
    const int nb = blockIdx.x * 64, kb = blockIdx.y * 64, e = blockIdx.z;
    __shared__ unsigned short t_[64][68];
    const int tid = threadIdx.x;
    const float* s = src + ((size_t)e * K + kb) * N + nb;
    {
        int kk = tid >> 4, n4 = (tid & 15) * 4;
#pragma unroll
        for (int i = 0; i < 4; ++i) {
            int k = kk + i * 16;
            vf4 v = *(const vf4*)(s + (size_t)k * N + n4);
#pragma unroll
            for (int j = 0; j < 4; ++j) t_[n4 + j][k] = f2bf(v[j]);
        }
    }
    __syncthreads();
    {
        int n = tid >> 2, c = (tid & 3) * 16;
        unsigned short* d = dst + ((size_t)e * N + nb + n) * K + kb + c;
        uint4 u0 = *(const uint4*)&t_[n][c];
        uint4 u1 = *(const uint4*)&t_[n][c + 8];
        *(uint4*)(d) = u0;
        *(uint4*)(d + 8) = u1;
    }
}

// ---------------- offsets ----------------
__global__ void k_offsets(const int* __restrict__ counts, int* __restrict__ offs)
{
    if (threadIdx.x == 0) {
        int s = 0;
#pragma unroll
        for (int e = 0; e < EE; ++e) { offs[e] = s; s += counts[e]; }
        offs[EE] = s;
    }
}

// ---------------- scatter ----------------
__global__ void k_scatter(const int* __restrict__ tke, const float* __restrict__ tkw,
                          const int* __restrict__ offs, int* __restrict__ cursor,
                          int* __restrict__ row_tok, int* __restrict__ row_slot,
                          float* __restrict__ row_w)
{
    int t = blockIdx.x * 256 + threadIdx.x;
    if (t >= TT) return;
#pragma unroll
    for (int k = 0; k < 2; ++k) {
        int e = tke[t * 2 + k];
        int pos = atomicAdd(&cursor[e], 1);
        int r = offs[e] + pos;
        row_tok[r] = t;
        row_slot[r] = k;
        row_w[r] = tkw[t * 2 + k];
    }
}

// ---------------- GEMM1: h = silu(x*WgT^t)*(x*WuT^t); BM=128,BN=64 dual ------------
// single-buffer 32KB, m97 2-barrier schedule, 4 blocks/CU
__global__ __launch_bounds__(256, 4)
void k_gemm1(const unsigned short* __restrict__ xb,
             const unsigned short* __restrict__ wgT, const unsigned short* __restrict__ wuT,
             const int* __restrict__ offs, const int* __restrict__ row_tok,
             unsigned short* __restrict__ hb)
{
    const int nbase = blockIdx.x * 64;
    const int e = blockIdx.y >> 4, mt = blockIdx.y & 15;
    const int seg0 = offs[e], n_e = offs[e + 1] - seg0;
    const int m0 = mt * 128;
    if (m0 >= n_e) return;

    __shared__ __align__(16) unsigned char smem[32768];  // A 16K | Bg 8K | Bu 8K
    const int tid = threadIdx.x, lane = tid & 63, wid = tid >> 6;
    const int wr = wid >> 1, wc = wid & 1;
    const int rl = lane >> 3, cbyte = (lane & 7) * 16;

    // pre-swizzled global sources: LDS slot (row, c) gets global (row, c ^ ((row&7)<<4))
    const char* a_src[4];
#pragma unroll
    for (int i = 0; i < 4; ++i) {
        int r = wid * 32 + i * 8 + rl;
        int gi = m0 + r; int cidx = gi < n_e ? gi : n_e - 1;
        int tok = row_tok[seg0 + cidx];
        a_src[i] = (const char*)xb + (size_t)tok * (HH * 2)
                 + (size_t)(cbyte ^ ((r & 7) << 4));
    }
    const char* bg_src[2]; const char* bu_src[2];
#pragma unroll
    for (int i = 0; i < 2; ++i) {
        int n = wid * 16 + i * 8 + rl;
        size_t rowoff = ((size_t)e * FF + nbase + n) * (HH * 2)
                      + (size_t)(cbyte ^ ((n & 7) << 4));
        bg_src[i] = (const char*)wgT + rowoff;
        bu_src[i] = (const char*)wuT + rowoff;
    }

    auto STAGE = [&](int kt) {
        size_t ko = (size_t)kt * 128;
#pragma unroll
        for (int i = 0; i < 4; ++i) gll16(a_src[i] + ko, smem + wid * 4096 + i * 1024);
#pragma unroll
        for (int i = 0; i < 2; ++i) gll16(bg_src[i] + ko, smem + 16384 + wid * 2048 + i * 1024);
#pragma unroll
        for (int i = 0; i < 2; ++i) gll16(bu_src[i] + ko, smem + 24576 + wid * 2048 + i * 1024);
    };

    f32x4v zero4 = {0.f, 0.f, 0.f, 0.f};
    f32x4v accg[4][2], accu[4][2];
#pragma unroll
    for (int mi = 0; mi < 4; ++mi)
#pragma unroll
        for (int ni = 0; ni < 2; ++ni) { accg[mi][ni] = zero4; accu[mi][ni] = zero4; }

    for (int kt = 0; kt < KT1; ++kt) {
        STAGE(kt);
        __syncthreads();   // drains vmcnt(0): staged data visible
#pragma unroll
        for (int kk = 0; kk < 2; ++kk) {
            const int cb = kk * 64 + ((lane >> 4) << 4);
            bf16x8 af[4], bgf[2], buf_[2];
#pragma unroll
            for (int mi = 0; mi < 4; ++mi) {
                int r = wr * 64 + mi * 16 + (lane & 15);
                af[mi] = *(const bf16x8*)(smem + r * 128 + (cb ^ ((r & 7) << 4)));
            }
#pragma unroll
            for (int ni = 0; ni < 2; ++ni) {
                int n = wc * 32 + ni * 16 + (lane & 15);
                int off = n * 128 + (cb ^ ((n & 7) << 4));
                bgf[ni]  = *(const bf16x8*)(smem + 16384 + off);
                buf_[ni] = *(const bf16x8*)(smem + 24576 + off);
            }
#pragma unroll
            for (int mi = 0; mi < 4; ++mi)
#pragma unroll
                for (int ni = 0; ni < 2; ++ni) {
                    accg[mi][ni] = __builtin_amdgcn_mfma_f32_16x16x32_bf16(af[mi], bgf[ni],  accg[mi][ni], 0, 0, 0);
                    accu[mi][ni] = __builtin_amdgcn_mfma_f32_16x16x32_bf16(af[mi], buf_[ni], accu[mi][ni], 0, 0, 0);
                }
        }
        __syncthreads();   // all reads done before next overwrite
    }

    const int lr = lane >> 4, lc = lane & 15;
#pragma unroll
    for (int mi = 0; mi < 4; ++mi) {
#pragma unroll
        for (int reg = 0; reg < 4; ++reg) {
            int r = wr * 64 + mi * 16 + lr * 4 + reg;
            int gi = m0 + r;
            if (gi < n_e) {
                size_t base = (size_t)(seg0 + gi) * FF;
#pragma unroll
                for (int ni = 0; ni < 2; ++ni) {
                    float g = accg[mi][ni][reg];
                    float u = accu[mi][ni][reg];
                    float hv = g * u / (1.f + __expf(-g));
                    int col = nbase + wc * 32 + ni * 16 + lc;
                    hb[base + col] = f2bf(hv);
                }
            }
        }
    }
}

// ---------------- GEMM2: y = h*WdT^t; BM=128,BN=128, split-K=4 ---------------------
// single-buffer 32KB, m97 2-barrier schedule, 4 blocks/CU
__global__ __launch_bounds__(256, 4)
void k_gemm2(const unsigned short* __restrict__ hb, const unsigned short* __restrict__ wdT,
             const int* __restrict__ offs, const int* __restrict__ row_tok,
             const int* __restrict__ row_slot, const float* __restrict__ row_w,
             float* __restrict__ opart)
{
    const int nbase = blockIdx.x * 128;
    const int e = blockIdx.y >> 4, mt = blockIdx.y & 15;
    const int ks = blockIdx.z;
    const int seg0 = offs[e], n_e = offs[e + 1] - seg0;
    const int m0 = mt * 128;
    if (m0 >= n_e) return;
    const int kt0 = ks * KTPER;

    __shared__ __align__(16) unsigned char smem[32768];  // A 16K | B 16K
    const int tid = threadIdx.x, lane = tid & 63, wid = tid >> 6;
    const int wr = wid >> 1, wc = wid & 1;
    const int rl = lane >> 3, cbyte = (lane & 7) * 16;

    const char* a_src[4];
#pragma unroll
    for (int i = 0; i < 4; ++i) {
        int r = wid * 32 + i * 8 + rl;
        int gi = m0 + r; int cidx = gi < n_e ? gi : n_e - 1;
        a_src[i] = (const char*)hb + (size_t)(seg0 + cidx) * (FF * 2)
                 + (size_t)(cbyte ^ ((r & 7) << 4));
    }
    const char* b_src[4];
#pragma unroll
    for (int i = 0; i < 4; ++i) {
        int n = wid * 32 + i * 8 + rl;
        b_src[i] = (const char*)wdT + ((size_t)e * HH + nbase + n) * (FF * 2)
                 + (size_t)(cbyte ^ ((n & 7) << 4));
    }

    auto STAGE = [&](int kt) {
        size_t ko = (size_t)kt * 128;
#pragma unroll
        for (int i = 0; i < 4; ++i) gll16(a_src[i] + ko, smem + wid * 4096 + i * 1024);
#pragma unroll
        for (int i = 0; i < 4; ++i) gll16(b_src[i] + ko, smem + 16384 + wid * 4096 + i * 1024);
    };

    f32x4v zero4 = {0.f, 0.f, 0.f, 0.f};
    f32x4v acc[4][4];
#pragma unroll
    for (int mi = 0; mi < 4; ++mi)
#pragma unroll
        for (int ni = 0; ni < 4; ++ni) acc[mi][ni] = zero4;

    for (int it = 0; it < KTPER; ++it) {
        STAGE(kt0 + it);
        __syncthreads();
#pragma unroll
        for (int kk = 0; kk < 2; ++kk) {
            const int cb = kk * 64 + ((lane >> 4) << 4);
            bf16x8 af[4], bf_[4];
#pragma unroll
            for (int mi = 0; mi < 4; ++mi) {
                int r = wr * 64 + mi * 16 + (lane & 15);
                af[mi] = *(const bf16x8*)(smem + r * 128 + (cb ^ ((r & 7) << 4)));
            }
#pragma unroll
            for (int ni = 0; ni < 4; ++ni) {
                int n = wc * 64 + ni * 16 + (lane & 15);
                bf_[ni] = *(const bf16x8*)(smem + 16384 + n * 128 + (cb ^ ((n & 7) << 4)));
            }
#pragma unroll
            for (int mi = 0; mi < 4; ++mi)
#pragma unroll
                for (int ni = 0; ni < 4; ++ni)
                    acc[mi][ni] = __builtin_amdgcn_mfma_f32_16x16x32_bf16(af[mi], bf_[ni], acc[mi][ni], 0, 0, 0);
        }
        __syncthreads();
    }

    const int lr = lane >> 4, lc = lane & 15;
#pragma unroll
    for (int mi = 0; mi < 4; ++mi) {
#pragma unroll
        for (int reg = 0; reg < 4; ++reg) {
            int r = wr * 64 + mi * 16 + lr * 4 + reg;
            int gi = m0 + r;
            if (gi < n_e) {
                int ar  = seg0 + gi;
                int tok = row_tok[ar];
                int sl  = row_slot[ar];
                float wgt = row_w[ar];
                size_t base = ((size_t)(ks * 2 + sl) * TT + tok) * HH;
#pragma unroll
                for (int ni = 0; ni < 4; ++ni) {
                    int col = nbase + wc * 64 + ni * 16 + lc;
                    opart[base + col] = wgt * acc[mi][ni][reg];
                }
            }
        }
    }
}

// ---------------- combine: out = sum of 8 fp32 slices ----------------
__global__ void k_combine(const float* __restrict__ opart, float* __restrict__ out)
{
    int i = (blockIdx.x * 256 + threadIdx.x) * 4;
    vf4 s = {0.f, 0.f, 0.f, 0.f};
#pragma unroll
    for (int k = 0; k < KS * 2; ++k)
        s += *(const vf4*)(opart + (size_t)k * TT * HH + i);
    *(vf4*)(out + i) = s;
}

extern "C" void kernel_launch(void* const* d_in, const int* in_sizes, int n_in,
                              void* d_out, int out_size, void* d_ws, size_t ws_size,
                              hipStream_t stream)
{
    (void)in_sizes; (void)n_in; (void)out_size; (void)ws_size;
    const float* x  = (const float*)d_in[0];
    const float* rw = (const float*)d_in[1];
    const float* wg = (const float*)d_in[2];
    const float* wu = (const float*)d_in[3];
    const float* wd = (const float*)d_in[4];
    float* out = (float*)d_out;

    char* ws = (char*)d_ws;
    size_t off = 0;
    auto alloc = [&](size_t b) { size_t o = off; off += (b + 255) & ~(size_t)255; return o; };
    unsigned short* xb  = (unsigned short*)(ws + alloc((size_t)TT * HH * 2));
    unsigned short* wgT = (unsigned short*)(ws + alloc((size_t)EE * FF * HH * 2));
    unsigned short* wuT = (unsigned short*)(ws + alloc((size_t)EE * FF * HH * 2));
    unsigned short* wdT = (unsigned short*)(ws + alloc((size_t)EE * HH * FF * 2));
    int*   tke      = (int*)  (ws + alloc((size_t)TT * 2 * 4));
    float* tkw      = (float*)(ws + alloc((size_t)TT * 2 * 4));
    int*   counts   = (int*)  (ws + alloc(EE * 4));
    int*   cursor   = (int*)  (ws + alloc(EE * 4));
    int*   offs     = (int*)  (ws + alloc((EE + 1) * 4));
    int*   row_tok  = (int*)  (ws + alloc((size_t)NROWS * 4));
    int*   row_slot = (int*)  (ws + alloc((size_t)NROWS * 4));
    float* row_w    = (float*)(ws + alloc((size_t)NROWS * 4));
    unsigned short* hb = (unsigned short*)(ws + alloc((size_t)NROWS * FF * 2));
    // opart (8 slices x 8.4 MB = 67 MB) aliases the wgT+wuT region (92 MB),
    // dead after k_gemm1 completes (stream-ordered before k_gemm2).
    float* opart = (float*)wgT;

    hipMemsetAsync(counts, 0, EE * 4, stream);
    hipMemsetAsync(cursor, 0, EE * 4, stream);

    k_convert_x<<<(TT * HH) / (256 * 8), 256, 0, stream>>>(x, xb);
    {
        dim3 gw(FF / 64, HH / 64, EE);   // wg/wu: K=HH, N=FF
        k_convert_wT<<<gw, 256, 0, stream>>>(wg, wgT, HH, FF);
        k_convert_wT<<<gw, 256, 0, stream>>>(wu, wuT, HH, FF);
        dim3 gd(HH / 64, FF / 64, EE);   // wd: K=FF, N=HH
        k_convert_wT<<<gd, 256, 0, stream>>>(wd, wdT, FF, HH);
    }
    k_router<<<TT / 4, 256, 0, stream>>>(x, rw, tke, tkw, counts);
    k_offsets<<<1, 64, 0, stream>>>(counts, offs);
    k_scatter<<<(TT + 255) / 256, 256, 0, stream>>>(tke, tkw, offs, cursor,
                                                    row_tok, row_slot, row_w);
    dim3 g1(FF / 64, 16 * EE);
    k_gemm1<<<g1, 256, 0, stream>>>(xb, wgT, wuT, offs, row_tok, hb);
    dim3 g2(HH / 128, 16 * EE, KS);
    k_gemm2<<<g2, 256, 0, stream>>>(hb, wdT, offs, row_tok, row_slot, row_w, opart);
    k_combine<<<(TT * HH) / (256 * 4), 256, 0, stream>>>(opart, out);
}